// Round 2
// baseline (239.768 us; speedup 1.0000x reference)
//
#include <hip/hip_runtime.h>
#include <math.h>

// ScoreFPELoss — analytic closed-form pipeline (fp32), 7 kernels.
//
// Derivation (per sample; W1x = W1[0:64,:], w1t = W1[64,:]):
//   z1 = W1x^T x + t*w1t + b1 ; h1 = tanh(z1); a1 = 1-h1^2
//   z2 = W2^T h1 + b2         ; h2 = tanh(z2); a2 = 1-h2^2
//   s  = W3^T h2 + b3
//   s_t = (a2 .* (W2^T (a1 .* w1t))) . w3sum,  w3sum_l = sum_k W3[l,k]
//   div = a1^T C a2,  C = W2 .* (W1x^T W3^T)   (precomputed, sample-independent)
//   u = C a2 ; v = C^T a1
//   t2 = a2 .* (W3 (2s+x) - 2 h2 .* v)
//   p  = a1 .* (W2 t2 - 2 h1 .* u)
//   g  = s + W1x p
//   out = mean_k | s_t - 0.5*beta*g_k |

#define Bsz 1024
#define Dd  64
#define Hh  512

// ---------------- KPRE: C = W2 .* (W1x^T @ W3^T); W3T; W1xT; w3sum; zero s_t ----------------
__global__ __launch_bounds__(256) void kpre(const float* __restrict__ W1,
                                            const float* __restrict__ W3,
                                            const float* __restrict__ W2,
                                            float* __restrict__ C,
                                            float* __restrict__ W3T,
                                            float* __restrict__ W1xT,
                                            float* __restrict__ w3sum,
                                            float* __restrict__ s_t) {
  const int b = blockIdx.x;
  const int tid = threadIdx.x;
  if (b < 64) {
    // C-tile (64x64) at (bj, bl)
    __shared__ float W1s[64][68];  // [i][j]
    __shared__ float W3s[64][68];  // [i][l]
    const int bj = (b & 7) * 64, bl = (b >> 3) * 64;
    for (int q = 0; q < 16; q++) {
      int idx = tid + q * 256;
      int i = idx >> 6, j = idx & 63;
      W1s[i][j] = W1[i * Hh + bj + j];
    }
    for (int q = 0; q < 16; q++) {
      int idx = tid + q * 256;
      int l = idx >> 6, i = idx & 63;
      W3s[i][l] = W3[(bl + l) * Dd + i];
    }
    __syncthreads();
    const int tj = (tid >> 4) << 2, tl = (tid & 15) << 2;
    float acc[4][4] = {};
#pragma unroll 8
    for (int i = 0; i < 64; i++) {
      float4 a = *(const float4*)&W1s[i][tj];
      float4 bb = *(const float4*)&W3s[i][tl];
      float ar[4] = {a.x, a.y, a.z, a.w};
      float br[4] = {bb.x, bb.y, bb.z, bb.w};
#pragma unroll
      for (int r = 0; r < 4; r++)
#pragma unroll
        for (int c = 0; c < 4; c++) acc[r][c] += ar[r] * br[c];
    }
#pragma unroll
    for (int r = 0; r < 4; r++) {
      int j = bj + tj + r;
      float4 cv;
#pragma unroll
      for (int c = 0; c < 4; c++)
        ((float*)&cv)[c] = W2[j * Hh + bl + tl + c] * acc[r][c];
      *(float4*)&C[j * Hh + bl + tl] = cv;
    }
  } else {
    // transposes + w3sum + s_t zero
    int gid = (b - 64) * 256 + tid;  // [0, 4096)
#pragma unroll
    for (int q = 0; q < 8; q++) {
      int e = gid + q * 4096;  // 32768 = 512*64
      int l = e >> 6, k = e & 63;
      W3T[k * Hh + l] = W3[e];
    }
#pragma unroll
    for (int q = 0; q < 8; q++) {
      int e = gid + q * 4096;  // 32768 = 64*512
      int i = e >> 9, j = e & 511;
      W1xT[j * Dd + i] = W1[e];
    }
    if (gid < Hh) {
      float sacc = 0.f;
      for (int k = 0; k < 64; k++) sacc += W3[gid * Dd + k];
      w3sum[gid] = sacc;
    }
    if (gid < Bsz) s_t[gid] = 0.f;
  }
}

// ---------------- K1: h1, a1, dh1t  ([1024,64]@[64,512]) ----------------
__global__ __launch_bounds__(256) void k1_h1(const float* __restrict__ X,
                                             const float* __restrict__ tt,
                                             const float* __restrict__ W1,
                                             const float* __restrict__ b1,
                                             float* __restrict__ h1,
                                             float* __restrict__ a1,
                                             float* __restrict__ dh1t) {
  __shared__ float As[64][68];  // [k][i]
  __shared__ float Bs[64][68];  // [k][n]
  const int i0 = blockIdx.x * 64, n0 = blockIdx.y * 64;
  const int tid = threadIdx.x;
  for (int q = 0; q < 16; q++) {
    int idx = tid + q * 256;
    int i = idx >> 6, k = idx & 63;
    As[k][i] = X[(i0 + i) * Dd + k];
  }
  for (int q = 0; q < 16; q++) {
    int idx = tid + q * 256;
    int k = idx >> 6, n = idx & 63;
    Bs[k][n] = W1[k * Hh + n0 + n];
  }
  __syncthreads();
  const int ti = (tid >> 4) << 2, tn = (tid & 15) << 2;
  float acc[4][4] = {};
#pragma unroll 8
  for (int k = 0; k < 64; k++) {
    float4 a = *(const float4*)&As[k][ti];
    float4 b = *(const float4*)&Bs[k][tn];
    float ar[4] = {a.x, a.y, a.z, a.w};
    float br[4] = {b.x, b.y, b.z, b.w};
#pragma unroll
    for (int r = 0; r < 4; r++)
#pragma unroll
      for (int c = 0; c < 4; c++) acc[r][c] += ar[r] * br[c];
  }
  const int nb = n0 + tn;
  float4 wtv = *(const float4*)&W1[Dd * Hh + nb];
  float4 b1v = *(const float4*)&b1[nb];
#pragma unroll
  for (int r = 0; r < 4; r++) {
    int i = i0 + ti + r;
    float tv = tt[i];
    float4 hv, av, dv;
#pragma unroll
    for (int c = 0; c < 4; c++) {
      float wt = ((float*)&wtv)[c];
      float z = acc[r][c] + tv * wt + ((float*)&b1v)[c];
      float h = tanhf(z);
      float a = 1.f - h * h;
      ((float*)&hv)[c] = h;
      ((float*)&av)[c] = a;
      ((float*)&dv)[c] = a * wt;
    }
    *(float4*)&h1[i * Hh + nb] = hv;
    *(float4*)&a1[i * Hh + nb] = av;
    *(float4*)&dh1t[i * Hh + nb] = dv;
  }
}

// ---------------- K2: h2, a2 + fused s_t (double GEMM [1024,512]@[512,512]) ----------------
__global__ __launch_bounds__(256) void k2_h2(const float* __restrict__ h1,
                                             const float* __restrict__ dh1t,
                                             const float* __restrict__ W2,
                                             const float* __restrict__ b2,
                                             const float* __restrict__ w3s,
                                             float* __restrict__ h2,
                                             float* __restrict__ a2,
                                             float* __restrict__ s_t) {
  __shared__ float A1s[32][36], A2s[32][36], Bs[32][68];
  const int i0 = blockIdx.x * 32, n0 = blockIdx.y * 64;
  const int tid = threadIdx.x;
  const int ti = (tid >> 4) << 1, tn = (tid & 15) << 2;
  const int ai = tid >> 5, ak = tid & 31;  // A stage: i = ai+q*8, k = ak
  const int bk = tid >> 6, bn = tid & 63;  // B stage: k = bk+q*4, n = bn
  float ra1[4], ra2[4], rb[8];
#pragma unroll
  for (int q = 0; q < 4; q++) {
    ra1[q] = h1[(i0 + ai + q * 8) * Hh + ak];
    ra2[q] = dh1t[(i0 + ai + q * 8) * Hh + ak];
  }
#pragma unroll
  for (int q = 0; q < 8; q++) rb[q] = W2[(bk + q * 4) * Hh + n0 + bn];
  float acc1[2][4] = {}, acc2[2][4] = {};
  for (int c = 0; c < 16; c++) {
    __syncthreads();
#pragma unroll
    for (int q = 0; q < 4; q++) {
      A1s[ak][ai + q * 8] = ra1[q];
      A2s[ak][ai + q * 8] = ra2[q];
    }
#pragma unroll
    for (int q = 0; q < 8; q++) Bs[bk + q * 4][bn] = rb[q];
    __syncthreads();
    if (c < 15) {
      int k0 = (c + 1) * 32;
#pragma unroll
      for (int q = 0; q < 4; q++) {
        ra1[q] = h1[(i0 + ai + q * 8) * Hh + k0 + ak];
        ra2[q] = dh1t[(i0 + ai + q * 8) * Hh + k0 + ak];
      }
#pragma unroll
      for (int q = 0; q < 8; q++) rb[q] = W2[(k0 + bk + q * 4) * Hh + n0 + bn];
    }
#pragma unroll 8
    for (int k = 0; k < 32; k++) {
      float2 a1v = *(const float2*)&A1s[k][ti];
      float2 a2v = *(const float2*)&A2s[k][ti];
      float4 bv = *(const float4*)&Bs[k][tn];
      float ar1[2] = {a1v.x, a1v.y}, ar2[2] = {a2v.x, a2v.y};
      float br[4] = {bv.x, bv.y, bv.z, bv.w};
#pragma unroll
      for (int r = 0; r < 2; r++)
#pragma unroll
        for (int cc = 0; cc < 4; cc++) {
          acc1[r][cc] += ar1[r] * br[cc];
          acc2[r][cc] += ar2[r] * br[cc];
        }
    }
  }
  const int nb = n0 + tn;
  float4 b2v = *(const float4*)&b2[nb];
  float4 w3v = *(const float4*)&w3s[nb];
#pragma unroll
  for (int r = 0; r < 2; r++) {
    int i = i0 + ti + r;
    float4 hv, av;
    float part = 0.f;
#pragma unroll
    for (int cc = 0; cc < 4; cc++) {
      float z = acc1[r][cc] + ((float*)&b2v)[cc];
      float h = tanhf(z);
      float a = 1.f - h * h;
      ((float*)&hv)[cc] = h;
      ((float*)&av)[cc] = a;
      part += a * acc2[r][cc] * ((float*)&w3v)[cc];  // dh2t . w3sum (partial)
    }
    *(float4*)&h2[i * Hh + nb] = hv;
    *(float4*)&a2[i * Hh + nb] = av;
#pragma unroll
    for (int off = 1; off < 16; off <<= 1) part += __shfl_xor(part, off, 64);
    if ((tid & 15) == 0) atomicAdd(&s_t[i], part);
  }
}

// ---------------- K34: s = W3^T h2 + b3 ; r3 = W3 (2s+x) ----------------
__global__ __launch_bounds__(256) void k34_s_r3(const float* __restrict__ h2,
                                                const float* __restrict__ W3,
                                                const float* __restrict__ W3T,
                                                const float* __restrict__ b3,
                                                const float* __restrict__ X,
                                                float* __restrict__ s,
                                                float* __restrict__ r3) {
  int i = (blockIdx.x * 256 + threadIdx.x) >> 6;
  int lam = threadIdx.x & 63;
  float sacc = b3[lam];
#pragma unroll
  for (int c = 0; c < 8; c++) {
    float hv = h2[i * Hh + c * 64 + lam];
#pragma unroll 8
    for (int k = 0; k < 64; k++) {
      float h = __shfl(hv, k, 64);
      sacc += h * W3[(c * 64 + k) * Dd + lam];
    }
  }
  s[i * Dd + lam] = sacc;
  float yv = 2.f * sacc + X[i * Dd + lam];
#pragma unroll
  for (int c = 0; c < 8; c++) {
    float acc = 0.f;
#pragma unroll 8
    for (int k = 0; k < 64; k++) {
      float yk = __shfl(yv, k, 64);
      acc += yk * W3T[k * Hh + c * 64 + lam];
    }
    r3[i * Hh + c * 64 + lam] = acc;
  }
}

// ---------------- K4b: u = C a2 ; t2 = a2.*(r3 - 2 h2.*(C^T a1)) ----------------
__global__ __launch_bounds__(256) void k4b_ut2(const float* __restrict__ a1,
                                               const float* __restrict__ a2,
                                               const float* __restrict__ h2,
                                               const float* __restrict__ r3,
                                               const float* __restrict__ C,
                                               float* __restrict__ u,
                                               float* __restrict__ t2) {
  __shared__ float A1s[32][36], A2s[32][36], Bus[32][68], Bvs[32][68];
  const int i0 = blockIdx.x * 32, n0 = blockIdx.y * 64;
  const int tid = threadIdx.x;
  const int ti = (tid >> 4) << 1, tn = (tid & 15) << 2;
  const int ai = tid >> 5, ak = tid & 31;
  const int bk = tid >> 6, bn = tid & 63;  // Bv stage (C rows = k)
  const int un = tid >> 5, uk = tid & 31;  // Bu stage (C rows = n)
  float ra1[4], ra2[4], rbu[8], rbv[8];
#pragma unroll
  for (int q = 0; q < 4; q++) {
    ra2[q] = a2[(i0 + ai + q * 8) * Hh + ak];
    ra1[q] = a1[(i0 + ai + q * 8) * Hh + ak];
  }
#pragma unroll
  for (int q = 0; q < 8; q++) {
    rbu[q] = C[(n0 + un + q * 8) * Hh + uk];
    rbv[q] = C[(bk + q * 4) * Hh + n0 + bn];
  }
  float accU[2][4] = {}, accV[2][4] = {};
  for (int c = 0; c < 16; c++) {
    __syncthreads();
#pragma unroll
    for (int q = 0; q < 4; q++) {
      A1s[ak][ai + q * 8] = ra1[q];
      A2s[ak][ai + q * 8] = ra2[q];
    }
#pragma unroll
    for (int q = 0; q < 8; q++) {
      Bus[uk][un + q * 8] = rbu[q];
      Bvs[bk + q * 4][bn] = rbv[q];
    }
    __syncthreads();
    if (c < 15) {
      int k0 = (c + 1) * 32;
#pragma unroll
      for (int q = 0; q < 4; q++) {
        ra2[q] = a2[(i0 + ai + q * 8) * Hh + k0 + ak];
        ra1[q] = a1[(i0 + ai + q * 8) * Hh + k0 + ak];
      }
#pragma unroll
      for (int q = 0; q < 8; q++) {
        rbu[q] = C[(n0 + un + q * 8) * Hh + k0 + uk];
        rbv[q] = C[(k0 + bk + q * 4) * Hh + n0 + bn];
      }
    }
#pragma unroll 8
    for (int k = 0; k < 32; k++) {
      float2 a2v = *(const float2*)&A2s[k][ti];
      float2 a1v = *(const float2*)&A1s[k][ti];
      float4 bu = *(const float4*)&Bus[k][tn];
      float4 bv = *(const float4*)&Bvs[k][tn];
      float ar2[2] = {a2v.x, a2v.y}, ar1[2] = {a1v.x, a1v.y};
      float bur[4] = {bu.x, bu.y, bu.z, bu.w};
      float bvr[4] = {bv.x, bv.y, bv.z, bv.w};
#pragma unroll
      for (int r = 0; r < 2; r++)
#pragma unroll
        for (int cc = 0; cc < 4; cc++) {
          accU[r][cc] += ar2[r] * bur[cc];
          accV[r][cc] += ar1[r] * bvr[cc];
        }
    }
  }
  const int nb = n0 + tn;
#pragma unroll
  for (int r = 0; r < 2; r++) {
    int i = i0 + ti + r;
    float4 a2f = *(const float4*)&a2[i * Hh + nb];
    float4 h2f = *(const float4*)&h2[i * Hh + nb];
    float4 r3f = *(const float4*)&r3[i * Hh + nb];
    float4 uv, t2v;
#pragma unroll
    for (int cc = 0; cc < 4; cc++) {
      ((float*)&uv)[cc] = accU[r][cc];
      ((float*)&t2v)[cc] = ((float*)&a2f)[cc] *
          (((float*)&r3f)[cc] - 2.f * ((float*)&h2f)[cc] * accV[r][cc]);
    }
    *(float4*)&u[i * Hh + nb] = uv;
    *(float4*)&t2[i * Hh + nb] = t2v;
  }
}

// ---------------- K5: p = a1 .* (W2 t2 - 2 h1 .* u) ----------------
__global__ __launch_bounds__(256) void k5_p(const float* __restrict__ t2,
                                            const float* __restrict__ W2,
                                            const float* __restrict__ a1,
                                            const float* __restrict__ h1,
                                            const float* __restrict__ u,
                                            float* __restrict__ p) {
  __shared__ float As[32][36], Bts[32][68];
  const int i0 = blockIdx.x * 32, n0 = blockIdx.y * 64;
  const int tid = threadIdx.x;
  const int ti = (tid >> 4) << 1, tn = (tid & 15) << 2;
  const int ai = tid >> 5, ak = tid & 31;
  const int un = tid >> 5, uk = tid & 31;
  float ra[4], rb[8];
#pragma unroll
  for (int q = 0; q < 4; q++) ra[q] = t2[(i0 + ai + q * 8) * Hh + ak];
#pragma unroll
  for (int q = 0; q < 8; q++) rb[q] = W2[(n0 + un + q * 8) * Hh + uk];
  float acc[2][4] = {};
  for (int c = 0; c < 16; c++) {
    __syncthreads();
#pragma unroll
    for (int q = 0; q < 4; q++) As[ak][ai + q * 8] = ra[q];
#pragma unroll
    for (int q = 0; q < 8; q++) Bts[uk][un + q * 8] = rb[q];
    __syncthreads();
    if (c < 15) {
      int k0 = (c + 1) * 32;
#pragma unroll
      for (int q = 0; q < 4; q++) ra[q] = t2[(i0 + ai + q * 8) * Hh + k0 + ak];
#pragma unroll
      for (int q = 0; q < 8; q++) rb[q] = W2[(n0 + un + q * 8) * Hh + k0 + uk];
    }
#pragma unroll 8
    for (int k = 0; k < 32; k++) {
      float2 av = *(const float2*)&As[k][ti];
      float4 bv = *(const float4*)&Bts[k][tn];
      float ar[2] = {av.x, av.y};
      float br[4] = {bv.x, bv.y, bv.z, bv.w};
#pragma unroll
      for (int r = 0; r < 2; r++)
#pragma unroll
        for (int cc = 0; cc < 4; cc++) acc[r][cc] += ar[r] * br[cc];
    }
  }
  const int nb = n0 + tn;
#pragma unroll
  for (int r = 0; r < 2; r++) {
    int i = i0 + ti + r;
    float4 a1f = *(const float4*)&a1[i * Hh + nb];
    float4 h1f = *(const float4*)&h1[i * Hh + nb];
    float4 uf  = *(const float4*)&u[i * Hh + nb];
    float4 pv;
#pragma unroll
    for (int cc = 0; cc < 4; cc++)
      ((float*)&pv)[cc] = ((float*)&a1f)[cc] *
          (acc[r][cc] - 2.f * ((float*)&h1f)[cc] * ((float*)&uf)[cc]);
    *(float4*)&p[i * Hh + nb] = pv;
  }
}

// ---------------- K6: g = s + W1x p ; out = mean_k |s_t - 0.5 beta g| ----------------
__global__ __launch_bounds__(256) void k6_loss(const float* __restrict__ p,
                                               const float* __restrict__ W1xT,
                                               const float* __restrict__ s,
                                               const float* __restrict__ s_t,
                                               const float* __restrict__ beta,
                                               float* __restrict__ out) {
  int i = (blockIdx.x * 256 + threadIdx.x) >> 6;
  int lam = threadIdx.x & 63;
  float g = s[i * Dd + lam];
#pragma unroll
  for (int c = 0; c < 8; c++) {
    float pv = p[i * Hh + c * 64 + lam];
#pragma unroll 8
    for (int jj = 0; jj < 64; jj++) {
      float pj = __shfl(pv, jj, 64);
      g += pj * W1xT[(c * 64 + jj) * Dd + lam];
    }
  }
  float e = fabsf(s_t[i] - 0.5f * beta[i] * g);
#pragma unroll
  for (int off = 32; off; off >>= 1) e += __shfl_down(e, off, 64);
  if (lam == 0) out[i] = e * (1.f / 64.f);
}

extern "C" void kernel_launch(void* const* d_in, const int* in_sizes, int n_in,
                              void* d_out, int out_size, void* d_ws, size_t ws_size,
                              hipStream_t stream) {
  const float* X    = (const float*)d_in[0];
  const float* tt   = (const float*)d_in[1];
  const float* beta = (const float*)d_in[2];
  const float* W1   = (const float*)d_in[3];
  const float* b1   = (const float*)d_in[4];
  const float* W2   = (const float*)d_in[5];
  const float* b2   = (const float*)d_in[6];
  const float* W3   = (const float*)d_in[7];
  const float* b3   = (const float*)d_in[8];
  float* out = (float*)d_out;

  float* ws   = (float*)d_ws;
  float* C    = ws;             // 512*512
  float* W3T  = C + 262144;     // [k][l] -> k*512+l
  float* W1xT = W3T + 32768;    // [j][i] -> j*64+i
  float* w3s  = W1xT + 32768;   // 512
  float* h1   = w3s + 512;      // each 1024*512 below
  float* a1   = h1 + 524288;
  float* dh1t = a1 + 524288;
  float* h2   = dh1t + 524288;
  float* a2v  = h2 + 524288;
  float* r3   = a2v + 524288;
  float* uu   = r3 + 524288;
  float* t2   = uu + 524288;
  float* pp   = t2 + 524288;
  float* ss   = pp + 524288;    // 1024*64
  float* st   = ss + 65536;     // 1024

  kpre<<<80, 256, 0, stream>>>(W1, W3, W2, C, W3T, W1xT, w3s, st);
  k1_h1<<<dim3(16, 8), 256, 0, stream>>>(X, tt, W1, b1, h1, a1, dh1t);
  k2_h2<<<dim3(32, 8), 256, 0, stream>>>(h1, dh1t, W2, b2, w3s, h2, a2v, st);
  k34_s_r3<<<256, 256, 0, stream>>>(h2, W3, W3T, b3, X, ss, r3);
  k4b_ut2<<<dim3(32, 8), 256, 0, stream>>>(a1, a2v, h2, r3, C, uu, t2);
  k5_p<<<dim3(32, 8), 256, 0, stream>>>(t2, W2, a1, h1, uu, pp);
  k6_loss<<<256, 256, 0, stream>>>(pp, W1xT, ss, st, beta, out);
}

// Round 9
// 199.120 us; speedup vs baseline: 1.2041x; 1.2041x over previous
//
#include <hip/hip_runtime.h>
#include <math.h>

// ScoreFPELoss — fully fused per-sample pipeline (fp32), 2 kernels.
// 512 threads/block, 4 samples/block, 256 blocks (8 waves/CU, 2/SIMD).
//
// Per sample (W1x = W1[0:64,:], w1t = W1[64,:]):
//   z1 = W1x^T x + t*w1t + b1 ; h1 = tanh(z1); a1 = 1-h1^2 ; q1 = a1.*w1t
//   z2 = W2^T h1 + b2         ; h2 = tanh(z2); a2 = 1-h2^2
//   dh2t = a2 .* (W2^T q1) ;  s_t = dh2t . w3sum
//   s  = W3^T h2 + b3 ;  y = 2s + x
//   r3[n] = sum_k W3[n,k] y[k]
//   u = C a2 ; v = C^T a1          (C = W2 .* (W1x^T W3^T), precomputed)
//   t2 = a2 .* (r3 - 2 h2 .* v)
//   p  = a1 .* (W2 t2 - 2 h1 .* u)
//   g  = s + W1x p
//   out = mean_d | s_t - 0.5*beta*g_d |

#define Bsz 1024
#define Dd  64
#define Hh  512

// ---------------- KPRE: C = W2 .* (W1x^T @ W3^T)  (blocks 0..63) ; w3sum (block 64) ----------------
__global__ __launch_bounds__(256) void kpre(const float* __restrict__ W1,
                                            const float* __restrict__ W3,
                                            const float* __restrict__ W2,
                                            float* __restrict__ C,
                                            float* __restrict__ w3sum) {
  const int b = blockIdx.x;
  const int tid = threadIdx.x;
  if (b < 64) {
    __shared__ float W1s[64][68];  // [d][j]
    __shared__ float W3s[64][68];  // [d][l]
    const int bj = (b & 7) * 64, bl = (b >> 3) * 64;
    for (int q = 0; q < 16; q++) {
      int idx = tid + q * 256;
      int i = idx >> 6, j = idx & 63;
      W1s[i][j] = W1[i * Hh + bj + j];
    }
    for (int q = 0; q < 16; q++) {
      int idx = tid + q * 256;
      int l = idx >> 6, i = idx & 63;
      W3s[i][l] = W3[(bl + l) * Dd + i];
    }
    __syncthreads();
    const int tj = (tid >> 4) << 2, tl = (tid & 15) << 2;
    float acc[4][4] = {};
#pragma unroll 8
    for (int i = 0; i < 64; i++) {
      float4 a = *(const float4*)&W1s[i][tj];
      float4 bb = *(const float4*)&W3s[i][tl];
      float ar[4] = {a.x, a.y, a.z, a.w};
      float br[4] = {bb.x, bb.y, bb.z, bb.w};
#pragma unroll
      for (int r = 0; r < 4; r++)
#pragma unroll
        for (int c = 0; c < 4; c++) acc[r][c] += ar[r] * br[c];
    }
#pragma unroll
    for (int r = 0; r < 4; r++) {
      int j = bj + tj + r;
      float4 cv;
#pragma unroll
      for (int c = 0; c < 4; c++)
        ((float*)&cv)[c] = W2[j * Hh + bl + tl + c] * acc[r][c];
      *(float4*)&C[j * Hh + bl + tl] = cv;
    }
  } else {
    // w3sum[n] = sum_k W3[n,k], sequential-k order
#pragma unroll
    for (int r = 0; r < 2; r++) {
      int n = tid + r * 256;
      float sacc = 0.f;
#pragma unroll 4
      for (int k4 = 0; k4 < 16; k4++) {
        float4 w = *(const float4*)&W3[n * Dd + k4 * 4];
        sacc += w.x; sacc += w.y; sacc += w.z; sacc += w.w;
      }
      w3sum[n] = sacc;
    }
  }
}

// ---------------- KFUSED: whole per-sample pipeline, 4 samples/block, 512 thr ----------------
__global__ __launch_bounds__(512) void kfused(const float* __restrict__ X,
                                              const float* __restrict__ tt,
                                              const float* __restrict__ beta,
                                              const float* __restrict__ W1,
                                              const float* __restrict__ b1,
                                              const float* __restrict__ W2,
                                              const float* __restrict__ b2,
                                              const float* __restrict__ W3,
                                              const float* __restrict__ b3,
                                              const float* __restrict__ C,
                                              const float* __restrict__ w3sum,
                                              float* __restrict__ out) {
  // activation LDS, interleaved [n][sample] so k-loop reads are b128 broadcasts
  __shared__ float xs[Dd * 4], ys[Dd * 4];
  __shared__ float h1s[Hh * 4], a1s[Hh * 4], q1s[Hh * 4];
  __shared__ float h2s[Hh * 4], a2s[Hh * 4], t2s[Hh * 4], ps[Hh * 4];
  __shared__ float sts[4], tb[4], bb4[4], red[32];
  __shared__ float ph[512];  // D/G half-partials, layout [ss][half][dd]

  const int tid = threadIdx.x;
  const int s0 = blockIdx.x * 4;
  const int n0 = tid;            // H-stage column (one per thread)
  const int dd = tid & 63;       // D-stage: dim = lane
  const int half = (tid >> 6) & 1;
  const int ss = tid >> 7;       // D-stage: sample

  // ---- Stage A: load x, t, beta ----
  if (tid < 256) {
    int sA = tid >> 6, dA = tid & 63;
    xs[dA * 4 + sA] = X[(s0 + sA) * Dd + dA];
  }
  if (tid < 4) tb[tid] = tt[s0 + tid];
  else if (tid < 8) bb4[tid - 4] = beta[s0 + tid - 4];
  __syncthreads();

  // ---- Stage B: layer 1 (K=64) ----
  {
    float acc[4] = {};
#pragma unroll 8
    for (int k = 0; k < Dd; k++) {
      float w = W1[k * Hh + n0];
      float4 xv = *(const float4*)&xs[k * 4];
#pragma unroll
      for (int s = 0; s < 4; s++) acc[s] += w * ((float*)&xv)[s];
    }
    float wt = W1[Dd * Hh + n0];
    float bc = b1[n0];
    float4 hv, av, qv;
#pragma unroll
    for (int s = 0; s < 4; s++) {
      float z = acc[s] + tb[s] * wt + bc;
      float h = tanhf(z);
      float a = 1.f - h * h;
      ((float*)&hv)[s] = h;
      ((float*)&av)[s] = a;
      ((float*)&qv)[s] = a * wt;
    }
    *(float4*)&h1s[n0 * 4] = hv;
    *(float4*)&a1s[n0 * 4] = av;
    *(float4*)&q1s[n0 * 4] = qv;
  }
  __syncthreads();

  // ---- Stage C: layer 2 + s_t partials (K=512, double GEMV) ----
  {
    float acc1[4] = {}, acc2[4] = {};
#pragma unroll 8
    for (int k = 0; k < Hh; k++) {
      float w = W2[k * Hh + n0];
      float4 hv = *(const float4*)&h1s[k * 4];
      float4 qv = *(const float4*)&q1s[k * 4];
#pragma unroll
      for (int s = 0; s < 4; s++) {
        acc1[s] += w * ((float*)&hv)[s];
        acc2[s] += w * ((float*)&qv)[s];
      }
    }
    float bc = b2[n0], wc = w3sum[n0];
    float stp[4];
    float4 hv, av;
#pragma unroll
    for (int s = 0; s < 4; s++) {
      float z = acc1[s] + bc;
      float h = tanhf(z);
      float a = 1.f - h * h;
      ((float*)&hv)[s] = h;
      ((float*)&av)[s] = a;
      stp[s] = a * acc2[s] * wc;  // dh2t . w3sum partial
    }
    *(float4*)&h2s[n0 * 4] = hv;
    *(float4*)&a2s[n0 * 4] = av;
#pragma unroll
    for (int off = 1; off < 64; off <<= 1)
#pragma unroll
      for (int s = 0; s < 4; s++) stp[s] += __shfl_xor(stp[s], off, 64);
    if (dd == 0)
#pragma unroll
      for (int s = 0; s < 4; s++) red[(tid >> 6) * 4 + s] = stp[s];
  }
  __syncthreads();
  if (tid < 4) {
    float t = 0.f;
#pragma unroll
    for (int w = 0; w < 8; w++) t += red[w * 4 + tid];
    sts[tid] = t;
  }

  // ---- Stage D: s = W3^T h2 + b3 ; y = 2s + x  (thread = (sample, half, dim)) ----
  {
    float sacc = half ? 0.f : b3[dd];
    const int l0 = half * 256;
#pragma unroll 8
    for (int l = l0; l < l0 + 256; l++)
      sacc += W3[l * Dd + dd] * h2s[l * 4 + ss];
    ph[tid] = sacc;
  }
  __syncthreads();
  float sval = 0.f;
  if (half == 0) {
    sval = ph[ss * 128 + dd] + ph[ss * 128 + 64 + dd];
    ys[dd * 4 + ss] = 2.f * sval + xs[dd * 4 + ss];
  }
  __syncthreads();

  // ---- Stage E: r3 (K=64); v = C^T a1, u = C a2 (K=512); t2 ----
  float ua[4] = {};
  {
    float r3a[4] = {};
#pragma unroll 4
    for (int k4 = 0; k4 < 16; k4++) {
      float4 w = *(const float4*)&W3[n0 * Dd + k4 * 4];
#pragma unroll
      for (int j = 0; j < 4; j++) {
        float4 yv = *(const float4*)&ys[(k4 * 4 + j) * 4];
#pragma unroll
        for (int s = 0; s < 4; s++) r3a[s] += ((float*)&w)[j] * ((float*)&yv)[s];
      }
    }
    float va[4] = {};
#pragma unroll 2
    for (int k4 = 0; k4 < 128; k4++) {
      float4 cu = *(const float4*)&C[n0 * Hh + k4 * 4];
#pragma unroll
      for (int j = 0; j < 4; j++) {
        int k = k4 * 4 + j;
        float cv = C[k * Hh + n0];
        float4 a1v = *(const float4*)&a1s[k * 4];
        float4 a2v = *(const float4*)&a2s[k * 4];
#pragma unroll
        for (int s = 0; s < 4; s++) {
          va[s] += cv * ((float*)&a1v)[s];
          ua[s] += ((float*)&cu)[j] * ((float*)&a2v)[s];
        }
      }
    }
    float4 a2r = *(const float4*)&a2s[n0 * 4];
    float4 h2r = *(const float4*)&h2s[n0 * 4];
    float4 t2v;
#pragma unroll
    for (int s = 0; s < 4; s++)
      ((float*)&t2v)[s] = ((float*)&a2r)[s] *
          (r3a[s] - 2.f * ((float*)&h2r)[s] * va[s]);
    *(float4*)&t2s[n0 * 4] = t2v;
  }
  __syncthreads();

  // ---- Stage F: p = a1 .* (W2 t2 - 2 h1 .* u) ----
  {
    float pa[4] = {};
#pragma unroll 2
    for (int k4 = 0; k4 < 128; k4++) {
      float4 w = *(const float4*)&W2[n0 * Hh + k4 * 4];
#pragma unroll
      for (int j = 0; j < 4; j++) {
        float4 t2v = *(const float4*)&t2s[(k4 * 4 + j) * 4];
#pragma unroll
        for (int s = 0; s < 4; s++) pa[s] += ((float*)&w)[j] * ((float*)&t2v)[s];
      }
    }
    float4 a1r = *(const float4*)&a1s[n0 * 4];
    float4 h1r = *(const float4*)&h1s[n0 * 4];
    float4 pv;
#pragma unroll
    for (int s = 0; s < 4; s++)
      ((float*)&pv)[s] = ((float*)&a1r)[s] *
          (pa[s] - 2.f * ((float*)&h1r)[s] * ua[s]);
    *(float4*)&ps[n0 * 4] = pv;
  }
  __syncthreads();

  // ---- Stage G: g = s + W1x p ; loss ----
  {
    float g = (half == 0) ? sval : 0.f;
    const int j0 = half * 256;
#pragma unroll 4
    for (int j4 = 0; j4 < 64; j4++) {
      float4 w = *(const float4*)&W1[dd * Hh + j0 + j4 * 4];
#pragma unroll
      for (int j = 0; j < 4; j++)
        g += ((float*)&w)[j] * ps[(j0 + j4 * 4 + j) * 4 + ss];
    }
    ph[tid] = g;
  }
  __syncthreads();
  if (half == 0) {
    float g = ph[ss * 128 + dd] + ph[ss * 128 + 64 + dd];
    float e = fabsf(sts[ss] - 0.5f * bb4[ss] * g);
#pragma unroll
    for (int off = 32; off; off >>= 1) e += __shfl_down(e, off, 64);
    if (dd == 0) out[s0 + ss] = e * (1.f / 64.f);
  }
}

extern "C" void kernel_launch(void* const* d_in, const int* in_sizes, int n_in,
                              void* d_out, int out_size, void* d_ws, size_t ws_size,
                              hipStream_t stream) {
  const float* X    = (const float*)d_in[0];
  const float* tt   = (const float*)d_in[1];
  const float* beta = (const float*)d_in[2];
  const float* W1   = (const float*)d_in[3];
  const float* b1   = (const float*)d_in[4];
  const float* W2   = (const float*)d_in[5];
  const float* b2   = (const float*)d_in[6];
  const float* W3   = (const float*)d_in[7];
  const float* b3   = (const float*)d_in[8];
  float* out = (float*)d_out;

  float* ws  = (float*)d_ws;
  float* C   = ws;            // 512*512
  float* w3s = C + 262144;    // 512

  kpre<<<65, 256, 0, stream>>>(W1, W3, W2, C, w3s);
  kfused<<<256, 512, 0, stream>>>(X, tt, beta, W1, b1, W2, b2, W3, b3, C, w3s, out);
}